// Round 9
// baseline (47.198 us; speedup 1.0000x reference)
//
#include <hip/hip_runtime.h>

#define BATCH 128
#define LEN 512
#define NCHUNK 4
#define CH_STEPS 128          // chunks 0-2: 128 steps; chunk 3: 127 (runtime bound)
#define STEPS_TOTAL 511
#define SIG_DIM 4680          // 8 + 64 + 512 + 4096
#define N_OUT 10
#define OFF2 8
#define OFF3 72
#define OFF4 584

typedef float v2f __attribute__((ext_vector_type(2)));

// ---------------------------------------------------------------------------
// Per-wave scan body. WV = wave index (compile-time) = owned i. nst runtime
// (128 or 127). Pipe split per step:
//   X[s+1]: 2x uniform VMEM/SMEM float4 (L1-resident)  ~8 cyc/wave
//   dx    : 4x v_pk_sub from prev-register pipeline
//   vj,vk : 2x ds_read_b32 broadcast (8 distinct addrs) ~12 LDS-cyc/wave
//   vi    : compile-time component of dx (WV)             0
//   s4    : 4x v_pk_fma + ~12 scalar VALU
// ---------------------------------------------------------------------------
template <int WV>
__device__ __forceinline__ void scan_body(const float4* __restrict__ Xf4, int s0,
                                          int nst, const float* __restrict__ dxs,
                                          float* __restrict__ o, int t) {
    const int j = (t >> 3) & 7, k = t & 7;
    float s1v = 0.f, s2v = 0.f, s3v = 0.f;
    v2f s4[4] = {{0.f, 0.f}, {0.f, 0.f}, {0.f, 0.f}, {0.f, 0.f}};

    v2f p0, p1, p2, p3;
    {
        const float4 pA = Xf4[s0 * 2], pB = Xf4[s0 * 2 + 1];
        p0 = (v2f){pA.x, pA.y}; p1 = (v2f){pA.z, pA.w};
        p2 = (v2f){pB.x, pB.y}; p3 = (v2f){pB.z, pB.w};
    }

    #pragma unroll 4
    for (int s = 0; s < nst; ++s) {
        const float4 cA = Xf4[(s0 + s + 1) * 2];      // uniform broadcast load
        const float4 cB = Xf4[(s0 + s + 1) * 2 + 1];
        const v2f c0 = (v2f){cA.x, cA.y}, c1 = (v2f){cA.z, cA.w};
        const v2f c2 = (v2f){cB.x, cB.y}, c3 = (v2f){cB.z, cB.w};
        const v2f d0 = c0 - p0, d1 = c1 - p1, d2 = c2 - p2, d3 = c3 - p3;
        p0 = c0; p1 = c1; p2 = c2; p3 = c3;

        const float vi = (WV == 0) ? d0.x : (WV == 1) ? d0.y : (WV == 2) ? d1.x :
                         (WV == 3) ? d1.y : (WV == 4) ? d2.x : (WV == 5) ? d2.y :
                         (WV == 6) ? d3.x : d3.y;
        const float vj = dxs[s * 8 + j];              // LDS broadcast
        const float vk = dxs[s * 8 + k];              // LDS broadcast

        const float t1 = s1v * vj;
        const float p  = vi * vj;
        // u = s2/2 + t1/6 + p/24 ; w = s2 + t1/2 + p/6   (old state)
        const float u  = fmaf(1.f / 24.f, p, fmaf(1.f / 6.f, t1, 0.5f * s2v));
        const float w  = fmaf(1.f / 6.f, p, fmaf(0.5f, t1, s2v));
        const float cc = fmaf(vk, u, s3v);            // level-4 coefficient
        const v2f cc2 = {cc, cc};
        s4[0] = __builtin_elementwise_fma(cc2, d0, s4[0]);
        s4[1] = __builtin_elementwise_fma(cc2, d1, s4[1]);
        s4[2] = __builtin_elementwise_fma(cc2, d2, s4[2]);
        s4[3] = __builtin_elementwise_fma(cc2, d3, s4[3]);
        s3v = fmaf(vk, w, s3v);
        s2v = fmaf(0.5f, p, s2v + t1);
        s1v += vi;
    }

    if ((t & 63) == 0) o[WV] = s1v;                    // s1[i], i == WV
    if ((t & 7) == 0)  o[OFF2 + (t >> 3)] = s2v;       // s2[ij]
    o[OFF3 + t] = s3v;
    *(float4*)&o[OFF4 + t * 8]     = make_float4(s4[0].x, s4[0].y, s4[1].x, s4[1].y);
    *(float4*)&o[OFF4 + t * 8 + 4] = make_float4(s4[2].x, s4[2].y, s4[3].x, s4[3].y);
}

// ---------------------------------------------------------------------------
// Kernel 1: per-(batch, quarter) depth-4 signature via Chen scan.
// Thread t owns (i,j,k) = (t>>6, (t>>3)&7, t&7); i == wave id.
// 512 blocks x 512 threads = 2 blocks/CU, 4 waves/SIMD (pipes overlap).
// ---------------------------------------------------------------------------
__global__ __launch_bounds__(512) void sig_chunk_kernel(const float* __restrict__ X,
                                                        float* __restrict__ sig) {
    const int wg = blockIdx.x;          // b * 4 + ch
    const int b  = wg >> 2;
    const int ch = wg & 3;
    const int s0 = ch * CH_STEPS;
    const int nst = (ch == 3) ? (STEPS_TOTAL - 3 * CH_STEPS) : CH_STEPS;  // 127 : 128
    const int t = threadIdx.x;

    __shared__ __align__(8) float dxs[CH_STEPS * 8];   // 4 KB, for vj/vk reads
    const float2* __restrict__ Xg2 = (const float2*)(X + ((size_t)b * LEN + s0) * 8);
    {
        float2 r = make_float2(0.f, 0.f);
        if ((t >> 2) < nst) {                          // guard chunk-3 pad row
            const float2 a = Xg2[t], c = Xg2[t + 4];
            r = make_float2(c.x - a.x, c.y - a.y);
        }
        ((float2*)dxs)[t] = r;
    }
    __syncthreads();

    const float4* __restrict__ Xf4 = (const float4*)(X + (size_t)b * LEN * 8);
    float* __restrict__ o = sig + (size_t)wg * SIG_DIM;
    switch (t >> 6) {
        case 0: scan_body<0>(Xf4, s0, nst, dxs, o, t); break;
        case 1: scan_body<1>(Xf4, s0, nst, dxs, o, t); break;
        case 2: scan_body<2>(Xf4, s0, nst, dxs, o, t); break;
        case 3: scan_body<3>(Xf4, s0, nst, dxs, o, t); break;
        case 4: scan_body<4>(Xf4, s0, nst, dxs, o, t); break;
        case 5: scan_body<5>(Xf4, s0, nst, dxs, o, t); break;
        case 6: scan_body<6>(Xf4, s0, nst, dxs, o, t); break;
        default: scan_body<7>(Xf4, s0, nst, dxs, o, t); break;
    }
}

// ---------------------------------------------------------------------------
// Chen combine: (A own-components in registers) ∘= (B cross-components via
// pointer -- global or LDS; addrspace resolved after inlining).
// ---------------------------------------------------------------------------
__device__ __forceinline__ void chen_combine(float& A1, float& A2, float& A3,
                                             float A4[8],
                                             const float* __restrict__ B,
                                             int i, int j, int k, int t) {
    const float B1i = B[i], B1j = B[j], B1k = B[k];
    const float4 b1a = *(const float4*)&B[0];
    const float4 b1b = *(const float4*)&B[4];
    const float B2ij = B[OFF2 + i * 8 + j];
    const float B2jk = B[OFF2 + j * 8 + k];
    const float4 b2a = *(const float4*)&B[OFF2 + k * 8];
    const float4 b2b = *(const float4*)&B[OFF2 + k * 8 + 4];
    const float B3ijk = B[OFF3 + t];
    const float4 b3a = *(const float4*)&B[OFF3 + (j * 8 + k) * 8];
    const float4 b3b = *(const float4*)&B[OFF3 + (j * 8 + k) * 8 + 4];
    const float4 b4a = *(const float4*)&B[OFF4 + t * 8];
    const float4 b4b = *(const float4*)&B[OFF4 + t * 8 + 4];

    // C4 = A4 + A3⊗B1 + A2⊗B2 + A1⊗B3 + B4   (old A1..A3)
    A4[0] += A3 * b1a.x + A2 * b2a.x + A1 * b3a.x + b4a.x;
    A4[1] += A3 * b1a.y + A2 * b2a.y + A1 * b3a.y + b4a.y;
    A4[2] += A3 * b1a.z + A2 * b2a.z + A1 * b3a.z + b4a.z;
    A4[3] += A3 * b1a.w + A2 * b2a.w + A1 * b3a.w + b4a.w;
    A4[4] += A3 * b1b.x + A2 * b2b.x + A1 * b3b.x + b4b.x;
    A4[5] += A3 * b1b.y + A2 * b2b.y + A1 * b3b.y + b4b.y;
    A4[6] += A3 * b1b.z + A2 * b2b.z + A1 * b3b.z + b4b.z;
    A4[7] += A3 * b1b.w + A2 * b2b.w + A1 * b3b.w + b4b.w;
    // C3 = A3 + A2⊗B1 + A1⊗B2 + B3
    A3 += A2 * B1k + A1 * B2jk + B3ijk;
    // C2 = A2 + A1⊗B1 + B2
    A2 += A1 * B1j + B2ij;
    // C1
    A1 += B1i;
}

// ---------------------------------------------------------------------------
// Kernel 2: pairwise Chen-combine tree (C01 = s0∘s1, C23 = s2∘s3 from global;
// C = C01∘C23 with C23 staged via LDS) + fused linear + block reduction.
// 128 blocks x 512 threads.
// ---------------------------------------------------------------------------
__global__ __launch_bounds__(512) void sig_combine_linear(const float* __restrict__ sig,
                                                          const float* __restrict__ W,
                                                          const float* __restrict__ bias,
                                                          float* __restrict__ out) {
    const int b = blockIdx.x;
    const int t = threadIdx.x;
    const int i = t >> 6, j = (t >> 3) & 7, k = t & 7;
    const float* __restrict__ S = sig + (size_t)b * NCHUNK * SIG_DIM;

    // C01 = chunk0 ∘ chunk1  (A own from global, B cross from global)
    float A1 = S[i];
    float A2 = S[OFF2 + i * 8 + j];
    float A3 = S[OFF3 + t];
    const float4 a4a = *(const float4*)&S[OFF4 + t * 8];
    const float4 a4b = *(const float4*)&S[OFF4 + t * 8 + 4];
    float A4[8] = {a4a.x, a4a.y, a4a.z, a4a.w, a4b.x, a4b.y, a4b.z, a4b.w};
    chen_combine(A1, A2, A3, A4, S + SIG_DIM, i, j, k, t);

    // C23 = chunk2 ∘ chunk3  (independent of C01 -> ILP)
    const float* __restrict__ S2 = S + 2 * SIG_DIM;
    float C1 = S2[i];
    float C2 = S2[OFF2 + i * 8 + j];
    float C3 = S2[OFF3 + t];
    const float4 c4a = *(const float4*)&S2[OFF4 + t * 8];
    const float4 c4b = *(const float4*)&S2[OFF4 + t * 8 + 4];
    float C4[8] = {c4a.x, c4a.y, c4a.z, c4a.w, c4b.x, c4b.y, c4b.z, c4b.w};
    chen_combine(C1, C2, C3, C4, S2 + SIG_DIM, i, j, k, t);

    // stage C23 to LDS (canonical owners, same layout as kernel-1 store)
    __shared__ __align__(16) float Bs[SIG_DIM];
    if ((t & 63) == 0) Bs[t >> 6] = C1;
    if ((t & 7) == 0)  Bs[OFF2 + (t >> 3)] = C2;
    Bs[OFF3 + t] = C3;
    *(float4*)&Bs[OFF4 + t * 8]     = make_float4(C4[0], C4[1], C4[2], C4[3]);
    *(float4*)&Bs[OFF4 + t * 8 + 4] = make_float4(C4[4], C4[5], C4[6], C4[7]);
    __syncthreads();

    // C = C01 ∘ C23
    chen_combine(A1, A2, A3, A4, Bs, i, j, k, t);

    // Fused linear: out[b][n] = sum_d sig[d] * W[n][d] + bias[n]
    float part[N_OUT];
    #pragma unroll
    for (int n = 0; n < N_OUT; ++n) {
        const float* __restrict__ Wn = W + (size_t)n * SIG_DIM;
        float p = A3 * Wn[OFF3 + t];
        const float4 w4a = *(const float4*)&Wn[OFF4 + t * 8];
        const float4 w4b = *(const float4*)&Wn[OFF4 + t * 8 + 4];
        p = fmaf(A4[0], w4a.x, p);
        p = fmaf(A4[1], w4a.y, p);
        p = fmaf(A4[2], w4a.z, p);
        p = fmaf(A4[3], w4a.w, p);
        p = fmaf(A4[4], w4b.x, p);
        p = fmaf(A4[5], w4b.y, p);
        p = fmaf(A4[6], w4b.z, p);
        p = fmaf(A4[7], w4b.w, p);
        if ((t & 7) == 0)  p = fmaf(A2, Wn[OFF2 + (t >> 3)], p);  // canonical s2 owner
        if ((t & 63) == 0) p = fmaf(A1, Wn[t >> 6], p);           // canonical s1 owner
        part[n] = p;
    }

    // wave reduce (64 lanes) then cross-wave via LDS
    #pragma unroll
    for (int n = 0; n < N_OUT; ++n) {
        #pragma unroll
        for (int off = 32; off > 0; off >>= 1)
            part[n] += __shfl_xor(part[n], off, 64);
    }
    __shared__ float red[8][N_OUT];
    const int wv = t >> 6, ln = t & 63;
    if (ln == 0) {
        #pragma unroll
        for (int n = 0; n < N_OUT; ++n) red[wv][n] = part[n];
    }
    __syncthreads();
    if (t < N_OUT) {
        float s = bias[t];
        #pragma unroll
        for (int w = 0; w < 8; ++w) s += red[w][t];
        out[b * N_OUT + t] = s;
    }
}

extern "C" void kernel_launch(void* const* d_in, const int* in_sizes, int n_in,
                              void* d_out, int out_size, void* d_ws, size_t ws_size,
                              hipStream_t stream) {
    const float* X    = (const float*)d_in[0];
    const float* W    = (const float*)d_in[1];
    const float* bias = (const float*)d_in[2];
    float* out = (float*)d_out;
    float* sig = (float*)d_ws;                 // NCHUNK*BATCH*SIG_DIM*4 ≈ 9.6 MB

    hipLaunchKernelGGL(sig_chunk_kernel, dim3(BATCH * NCHUNK), dim3(512), 0, stream, X, sig);
    hipLaunchKernelGGL(sig_combine_linear, dim3(BATCH), dim3(512), 0, stream, sig, W, bias, out);
}

// Round 10
// 43.358 us; speedup vs baseline: 1.0886x; 1.0886x over previous
//
#include <hip/hip_runtime.h>

#define BATCH 128
#define LEN 512
#define NCHUNK 8
#define CH_STEPS 64           // chunks 0-6: 64 steps; chunk 7: 63 (runtime bound)
#define STEPS_TOTAL 511
#define SIG_DIM 4680          // 8 + 64 + 512 + 4096
#define N_OUT 10
#define OFF2 8
#define OFF3 72
#define OFF4 584

typedef float v2f __attribute__((ext_vector_type(2)));

// ---------------------------------------------------------------------------
// Per-wave scan body. WV = wave index (compile-time) = owned i. nst runtime
// (64 or 63). Pipe split per step:
//   X[s+1]: 2x uniform VMEM float4 (L1-resident)       ~8 cyc/wave
//   dx    : 4x v_pk_sub from prev-register pipeline
//   vj,vk : 2x ds_read_b32 broadcast (8 distinct addrs) ~12 LDS-cyc/wave
//   vi    : compile-time component of dx (WV)             0
//   s4    : 4x v_pk_fma + ~12 scalar VALU
// ---------------------------------------------------------------------------
template <int WV>
__device__ __forceinline__ void scan_body(const float4* __restrict__ Xf4, int s0,
                                          int nst, const float* __restrict__ dxs,
                                          float* __restrict__ o, int t) {
    const int j = (t >> 3) & 7, k = t & 7;
    float s1v = 0.f, s2v = 0.f, s3v = 0.f;
    v2f s4[4] = {{0.f, 0.f}, {0.f, 0.f}, {0.f, 0.f}, {0.f, 0.f}};

    v2f p0, p1, p2, p3;
    {
        const float4 pA = Xf4[s0 * 2], pB = Xf4[s0 * 2 + 1];
        p0 = (v2f){pA.x, pA.y}; p1 = (v2f){pA.z, pA.w};
        p2 = (v2f){pB.x, pB.y}; p3 = (v2f){pB.z, pB.w};
    }
    const float4* __restrict__ Xn = Xf4 + (s0 + 1) * 2;

    #pragma unroll 4
    for (int s = 0; s < nst; ++s) {
        const float4 cA = Xn[s * 2];                  // uniform broadcast load
        const float4 cB = Xn[s * 2 + 1];
        const v2f c0 = (v2f){cA.x, cA.y}, c1 = (v2f){cA.z, cA.w};
        const v2f c2 = (v2f){cB.x, cB.y}, c3 = (v2f){cB.z, cB.w};
        const v2f d0 = c0 - p0, d1 = c1 - p1, d2 = c2 - p2, d3 = c3 - p3;
        p0 = c0; p1 = c1; p2 = c2; p3 = c3;

        const float vi = (WV == 0) ? d0.x : (WV == 1) ? d0.y : (WV == 2) ? d1.x :
                         (WV == 3) ? d1.y : (WV == 4) ? d2.x : (WV == 5) ? d2.y :
                         (WV == 6) ? d3.x : d3.y;
        const float vj = dxs[s * 8 + j];              // LDS broadcast
        const float vk = dxs[s * 8 + k];              // LDS broadcast

        const float t1 = s1v * vj;
        const float p  = vi * vj;
        // u = s2/2 + t1/6 + p/24 ; w = s2 + t1/2 + p/6   (old state)
        const float u  = fmaf(1.f / 24.f, p, fmaf(1.f / 6.f, t1, 0.5f * s2v));
        const float w  = fmaf(1.f / 6.f, p, fmaf(0.5f, t1, s2v));
        const float cc = fmaf(vk, u, s3v);            // level-4 coefficient
        const v2f cc2 = {cc, cc};
        s4[0] = __builtin_elementwise_fma(cc2, d0, s4[0]);
        s4[1] = __builtin_elementwise_fma(cc2, d1, s4[1]);
        s4[2] = __builtin_elementwise_fma(cc2, d2, s4[2]);
        s4[3] = __builtin_elementwise_fma(cc2, d3, s4[3]);
        s3v = fmaf(vk, w, s3v);
        s2v = fmaf(0.5f, p, s2v + t1);
        s1v += vi;
    }

    if ((t & 63) == 0) o[WV] = s1v;                    // s1[i], i == WV
    if ((t & 7) == 0)  o[OFF2 + (t >> 3)] = s2v;       // s2[ij]
    o[OFF3 + t] = s3v;
    *(float4*)&o[OFF4 + t * 8]     = make_float4(s4[0].x, s4[0].y, s4[1].x, s4[1].y);
    *(float4*)&o[OFF4 + t * 8 + 4] = make_float4(s4[2].x, s4[2].y, s4[3].x, s4[3].y);
}

// ---------------------------------------------------------------------------
// Kernel 1: per-(batch, eighth) depth-4 signature via Chen scan.
// Thread t owns (i,j,k) = (t>>6, (t>>3)&7, t&7); i == wave id.
// 1024 blocks x 512 threads = 4 blocks/CU, 8 waves/SIMD (full occupancy).
// ---------------------------------------------------------------------------
__global__ __launch_bounds__(512) void sig_chunk_kernel(const float* __restrict__ X,
                                                        float* __restrict__ sig) {
    const int wg = blockIdx.x;          // b * 8 + ch
    const int b  = wg >> 3;
    const int ch = wg & 7;
    const int s0 = ch * CH_STEPS;
    const int nst = (ch == 7) ? (STEPS_TOTAL - 7 * CH_STEPS) : CH_STEPS;  // 63 : 64
    const int t = threadIdx.x;

    __shared__ __align__(8) float dxs[CH_STEPS * 8];   // 2 KB, for vj/vk reads
    if (t < CH_STEPS * 4) {                            // 256 float2 slots
        const float2* __restrict__ Xg2 =
            (const float2*)(X + ((size_t)b * LEN + s0) * 8);
        float2 r = make_float2(0.f, 0.f);
        if ((t >> 2) < nst) {                          // guard chunk-7 pad row
            const float2 a = Xg2[t], c = Xg2[t + 4];
            r = make_float2(c.x - a.x, c.y - a.y);
        }
        ((float2*)dxs)[t] = r;
    }
    __syncthreads();

    const float4* __restrict__ Xf4 = (const float4*)(X + (size_t)b * LEN * 8);
    float* __restrict__ o = sig + (size_t)wg * SIG_DIM;
    switch (t >> 6) {
        case 0: scan_body<0>(Xf4, s0, nst, dxs, o, t); break;
        case 1: scan_body<1>(Xf4, s0, nst, dxs, o, t); break;
        case 2: scan_body<2>(Xf4, s0, nst, dxs, o, t); break;
        case 3: scan_body<3>(Xf4, s0, nst, dxs, o, t); break;
        case 4: scan_body<4>(Xf4, s0, nst, dxs, o, t); break;
        case 5: scan_body<5>(Xf4, s0, nst, dxs, o, t); break;
        case 6: scan_body<6>(Xf4, s0, nst, dxs, o, t); break;
        default: scan_body<7>(Xf4, s0, nst, dxs, o, t); break;
    }
}

// ---------------------------------------------------------------------------
// Chen combine: (A own-components in registers) ∘= (B cross-components via
// pointer -- global or LDS; addrspace resolved after inlining).
// ---------------------------------------------------------------------------
__device__ __forceinline__ void chen_combine(float& A1, float& A2, float& A3,
                                             float A4[8],
                                             const float* __restrict__ B,
                                             int i, int j, int k, int t) {
    const float B1i = B[i], B1j = B[j], B1k = B[k];
    const float4 b1a = *(const float4*)&B[0];
    const float4 b1b = *(const float4*)&B[4];
    const float B2ij = B[OFF2 + i * 8 + j];
    const float B2jk = B[OFF2 + j * 8 + k];
    const float4 b2a = *(const float4*)&B[OFF2 + k * 8];
    const float4 b2b = *(const float4*)&B[OFF2 + k * 8 + 4];
    const float B3ijk = B[OFF3 + t];
    const float4 b3a = *(const float4*)&B[OFF3 + (j * 8 + k) * 8];
    const float4 b3b = *(const float4*)&B[OFF3 + (j * 8 + k) * 8 + 4];
    const float4 b4a = *(const float4*)&B[OFF4 + t * 8];
    const float4 b4b = *(const float4*)&B[OFF4 + t * 8 + 4];

    // C4 = A4 + A3⊗B1 + A2⊗B2 + A1⊗B3 + B4   (old A1..A3)
    A4[0] += A3 * b1a.x + A2 * b2a.x + A1 * b3a.x + b4a.x;
    A4[1] += A3 * b1a.y + A2 * b2a.y + A1 * b3a.y + b4a.y;
    A4[2] += A3 * b1a.z + A2 * b2a.z + A1 * b3a.z + b4a.z;
    A4[3] += A3 * b1a.w + A2 * b2a.w + A1 * b3a.w + b4a.w;
    A4[4] += A3 * b1b.x + A2 * b2b.x + A1 * b3b.x + b4b.x;
    A4[5] += A3 * b1b.y + A2 * b2b.y + A1 * b3b.y + b4b.y;
    A4[6] += A3 * b1b.z + A2 * b2b.z + A1 * b3b.z + b4b.z;
    A4[7] += A3 * b1b.w + A2 * b2b.w + A1 * b3b.w + b4b.w;
    // C3 = A3 + A2⊗B1 + A1⊗B2 + B3
    A3 += A2 * B1k + A1 * B2jk + B3ijk;
    // C2 = A2 + A1⊗B1 + B2
    A2 += A1 * B1j + B2ij;
    // C1
    A1 += B1i;
}

__device__ __forceinline__ void load_own(const float* __restrict__ S,
                                         float& A1, float& A2, float& A3,
                                         float A4[8], int i, int j, int t) {
    A1 = S[i];
    A2 = S[OFF2 + i * 8 + j];
    A3 = S[OFF3 + t];
    const float4 a = *(const float4*)&S[OFF4 + t * 8];
    const float4 b = *(const float4*)&S[OFF4 + t * 8 + 4];
    A4[0] = a.x; A4[1] = a.y; A4[2] = a.z; A4[3] = a.w;
    A4[4] = b.x; A4[5] = b.y; A4[6] = b.z; A4[7] = b.w;
}

__device__ __forceinline__ void stage_lds(float* __restrict__ Bs,
                                          float A1, float A2, float A3,
                                          const float A4[8], int t) {
    if ((t & 63) == 0) Bs[t >> 6] = A1;
    if ((t & 7) == 0)  Bs[OFF2 + (t >> 3)] = A2;
    Bs[OFF3 + t] = A3;
    *(float4*)&Bs[OFF4 + t * 8]     = make_float4(A4[0], A4[1], A4[2], A4[3]);
    *(float4*)&Bs[OFF4 + t * 8 + 4] = make_float4(A4[4], A4[5], A4[6], A4[7]);
}

// ---------------------------------------------------------------------------
// Kernel 2: 3-level pairwise Chen-combine tree over 8 chunk signatures
// (level 1: C01,C23,C45,C67 from global; levels 2-3 via LDS staging)
// + fused linear + block reduction. 128 blocks x 512 threads.
// ---------------------------------------------------------------------------
__global__ __launch_bounds__(512) void sig_combine_linear(const float* __restrict__ sig,
                                                          const float* __restrict__ W,
                                                          const float* __restrict__ bias,
                                                          float* __restrict__ out) {
    const int b = blockIdx.x;
    const int t = threadIdx.x;
    const int i = t >> 6, j = (t >> 3) & 7, k = t & 7;
    const float* __restrict__ S = sig + (size_t)b * NCHUNK * SIG_DIM;

    __shared__ __align__(16) float Bs0[SIG_DIM];
    __shared__ __align__(16) float Bs1[SIG_DIM];

    // level 1 (all from global, L2-resident):
    // C23 -> LDS0, C67 -> LDS1 (computed first to free registers)
    {
        float C1, C2, C3, C4[8];
        load_own(S + 2 * SIG_DIM, C1, C2, C3, C4, i, j, t);
        chen_combine(C1, C2, C3, C4, S + 3 * SIG_DIM, i, j, k, t);
        stage_lds(Bs0, C1, C2, C3, C4, t);
    }
    {
        float C1, C2, C3, C4[8];
        load_own(S + 6 * SIG_DIM, C1, C2, C3, C4, i, j, t);
        chen_combine(C1, C2, C3, C4, S + 7 * SIG_DIM, i, j, k, t);
        stage_lds(Bs1, C1, C2, C3, C4, t);
    }

    // C01 (stays in registers as the running accumulator A)
    float A1, A2, A3, A4[8];
    load_own(S, A1, A2, A3, A4, i, j, t);
    chen_combine(A1, A2, A3, A4, S + SIG_DIM, i, j, k, t);

    // C45 (registers)
    float D1, D2, D3, D4[8];
    load_own(S + 4 * SIG_DIM, D1, D2, D3, D4, i, j, t);
    chen_combine(D1, D2, D3, D4, S + 5 * SIG_DIM, i, j, k, t);

    __syncthreads();                      // LDS0 = C23, LDS1 = C67 ready

    // level 2: A = C0123, D = C4567
    chen_combine(A1, A2, A3, A4, Bs0, i, j, k, t);
    chen_combine(D1, D2, D3, D4, Bs1, i, j, k, t);

    __syncthreads();                      // everyone done reading LDS0
    stage_lds(Bs0, D1, D2, D3, D4, t);
    __syncthreads();                      // LDS0 = C4567 ready

    // level 3: A = full signature
    chen_combine(A1, A2, A3, A4, Bs0, i, j, k, t);

    // Fused linear: out[b][n] = sum_d sig[d] * W[n][d] + bias[n]
    float part[N_OUT];
    #pragma unroll
    for (int n = 0; n < N_OUT; ++n) {
        const float* __restrict__ Wn = W + (size_t)n * SIG_DIM;
        float p = A3 * Wn[OFF3 + t];
        const float4 w4a = *(const float4*)&Wn[OFF4 + t * 8];
        const float4 w4b = *(const float4*)&Wn[OFF4 + t * 8 + 4];
        p = fmaf(A4[0], w4a.x, p);
        p = fmaf(A4[1], w4a.y, p);
        p = fmaf(A4[2], w4a.z, p);
        p = fmaf(A4[3], w4a.w, p);
        p = fmaf(A4[4], w4b.x, p);
        p = fmaf(A4[5], w4b.y, p);
        p = fmaf(A4[6], w4b.z, p);
        p = fmaf(A4[7], w4b.w, p);
        if ((t & 7) == 0)  p = fmaf(A2, Wn[OFF2 + (t >> 3)], p);  // canonical s2 owner
        if ((t & 63) == 0) p = fmaf(A1, Wn[t >> 6], p);           // canonical s1 owner
        part[n] = p;
    }

    // wave reduce (64 lanes) then cross-wave via LDS
    #pragma unroll
    for (int n = 0; n < N_OUT; ++n) {
        #pragma unroll
        for (int off = 32; off > 0; off >>= 1)
            part[n] += __shfl_xor(part[n], off, 64);
    }
    __shared__ float red[8][N_OUT];
    const int wv = t >> 6, ln = t & 63;
    if (ln == 0) {
        #pragma unroll
        for (int n = 0; n < N_OUT; ++n) red[wv][n] = part[n];
    }
    __syncthreads();
    if (t < N_OUT) {
        float s = bias[t];
        #pragma unroll
        for (int w = 0; w < 8; ++w) s += red[w][t];
        out[b * N_OUT + t] = s;
    }
}

extern "C" void kernel_launch(void* const* d_in, const int* in_sizes, int n_in,
                              void* d_out, int out_size, void* d_ws, size_t ws_size,
                              hipStream_t stream) {
    const float* X    = (const float*)d_in[0];
    const float* W    = (const float*)d_in[1];
    const float* bias = (const float*)d_in[2];
    float* out = (float*)d_out;
    float* sig = (float*)d_ws;                 // NCHUNK*BATCH*SIG_DIM*4 ≈ 19.2 MB

    hipLaunchKernelGGL(sig_chunk_kernel, dim3(BATCH * NCHUNK), dim3(512), 0, stream, X, sig);
    hipLaunchKernelGGL(sig_combine_linear, dim3(BATCH), dim3(512), 0, stream, sig, W, bias, out);
}